// Round 10
// baseline (512.256 us; speedup 1.0000x reference)
//
#include <hip/hip_runtime.h>
#include <hip/hip_bf16.h>
#include <hip/hip_fp16.h>

#define N_PTS 500000
#define P_POLY 50000
#define IN_DIM 9
#define HDIM 128
#define EPSV 1e-5f
#define BCAP 64
#define NG 7813            // ceil(N_PTS / 64) offset-window groups
#define CAPR 96            // row capacity per group (64 + max polyline len)
#define HS 136             // LDS row stride in elems (272 B): sagg gather tiles banks

typedef __attribute__((ext_vector_type(8))) short short8;
typedef __attribute__((ext_vector_type(4))) float floatx4;

__device__ __forceinline__ unsigned short f2h(float f) {
  return __half_as_ushort(__float2half(f));
}
__device__ __forceinline__ float h2f(unsigned short u) {
  return __half2float(__ushort_as_half(u));
}
// packed f16 max on raw bits (avoids ROCm 7.2 __half2/__hip_bfloat162 ctor aliasing)
__device__ __forceinline__ unsigned int pkmax(unsigned int a, unsigned int b) {
  unsigned int r;
  asm("v_pk_max_f16 %0, %1, %2" : "=v"(r) : "v"(a), "v"(b));
  return r;
}

// ---------------- bucket build ----------------
__global__ __launch_bounds__(256) void k_bucket(
    const int* __restrict__ ids, unsigned int* __restrict__ cnt, int* __restrict__ list)
{
  int i = blockIdx.x * blockDim.x + threadIdx.x;
  if (i < N_PTS) {
    int id = ids[i];
    unsigned k = atomicAdd(&cnt[id], 1u);
    list[id * BCAP + (k & (BCAP - 1))] = i;
  }
}

// ---------------- scan stage 1: per-block totals ----------------
__global__ __launch_bounds__(256) void k_scan1(
    const unsigned int* __restrict__ cnt, unsigned int* __restrict__ btot)
{
  __shared__ unsigned int s[256];
  int t = threadIdx.x;
  int i = blockIdx.x * 256 + t;
  s[t] = (i < P_POLY) ? cnt[i] : 0u;
  __syncthreads();
  for (int d = 128; d > 0; d >>= 1) {
    if (t < d) s[t] += s[t + d];
    __syncthreads();
  }
  if (t == 0) btot[blockIdx.x] = s[0];
}

// ---- scan stage 2: offsets + perm (sorted->orig) + group lists ----
__global__ __launch_bounds__(256) void k_scan2(
    const unsigned int* __restrict__ cnt, const unsigned int* __restrict__ btot,
    const int* __restrict__ list, unsigned int* __restrict__ offsets,
    int* __restrict__ perm, int* __restrict__ gcount, int* __restrict__ gplist)
{
  __shared__ unsigned int s[256];
  __shared__ unsigned int sbase;
  int b = blockIdx.x, t = threadIdx.x;
  int i = b * 256 + t;
  unsigned int v = (i < P_POLY) ? cnt[i] : 0u;
  s[t] = v;
  __syncthreads();
  for (int d = 1; d < 256; d <<= 1) {
    unsigned int tmp = (t >= d) ? s[t - d] : 0u;
    __syncthreads();
    s[t] += tmp;
    __syncthreads();
  }
  unsigned int incl = s[t];
  if (t == 0) {
    unsigned int base = 0;
    for (int j = 0; j < b; ++j) base += btot[j];
    sbase = base;
  }
  __syncthreads();
  unsigned int off = sbase + incl - v;  // exclusive prefix
  if (i < P_POLY) {
    offsets[i] = off;
    unsigned int n = v > BCAP ? (unsigned)BCAP : v;
    int g = (int)(off >> 6);
    int slot = atomicAdd(&gcount[g], 1);
    gplist[g * BCAP + (slot & (BCAP - 1))] = i;
    for (unsigned int k = 0; k < n; ++k)
      perm[off + k] = list[i * BCAP + k];
  }
}

// ---------------- W prep: split + transpose to f16 [col][128 k] ----------------
__global__ __launch_bounds__(256) void k_wprep(
    const float* __restrict__ W1, const float* __restrict__ W2,
    unsigned short* __restrict__ Wt1, unsigned short* __restrict__ Wb1,
    unsigned short* __restrict__ Wt2, unsigned short* __restrict__ Wb2)
{
  int idx = blockIdx.x * 256 + threadIdx.x;  // 256 blocks -> 65536
  int sel = idx >> 14;
  int e = idx & 16383;
  int c = e & 127;
  int k = e >> 7;
  const float* W = (sel < 2) ? W1 : W2;
  unsigned short* O = sel == 0 ? Wt1 : sel == 1 ? Wb1 : sel == 2 ? Wt2 : Wb2;
  int kg = k + ((sel & 1) ? 128 : 0);
  O[c * 128 + k] = f2h(W[kg * 128 + c]);
}

// ---------------- fused per-group network: MFMA layer helper ----------------
__device__ __forceinline__ void enc_layer(
    unsigned short* sh, const unsigned short* sagg, const int* pid_loc, char* smisc,
    const unsigned short* __restrict__ Wt, const unsigned short* __restrict__ Wb,
    const float* __restrict__ bias, const float* __restrict__ gamma,
    const float* __restrict__ beta, int w, int l15, int l4, int koff)
{
  const int c0 = w * 32 + l15;
  const int c1 = c0 + 16;
  floatx4 acc[6][2];
#pragma unroll
  for (int mt = 0; mt < 6; ++mt) {
    acc[mt][0] = (floatx4){0.f, 0.f, 0.f, 0.f};
    acc[mt][1] = (floatx4){0.f, 0.f, 0.f, 0.f};
  }
  int pl[6];
#pragma unroll
  for (int mt = 0; mt < 6; ++mt) pl[mt] = pid_loc[mt * 16 + l15];

#pragma unroll
  for (int kk = 0; kk < 4; ++kk) {
    short8 B0 = *reinterpret_cast<const short8*>(Wt + c0 * 128 + kk * 32 + koff);
    short8 B1 = *reinterpret_cast<const short8*>(Wt + c1 * 128 + kk * 32 + koff);
#pragma unroll
    for (int mt = 0; mt < 6; ++mt) {
      short8 a = *reinterpret_cast<const short8*>(sh + (mt * 16 + l15) * HS + kk * 32 + koff);
      acc[mt][0] = __builtin_amdgcn_mfma_f32_16x16x32_f16(a, B0, acc[mt][0], 0, 0, 0);
      acc[mt][1] = __builtin_amdgcn_mfma_f32_16x16x32_f16(a, B1, acc[mt][1], 0, 0, 0);
    }
  }
#pragma unroll
  for (int kk = 0; kk < 4; ++kk) {
    short8 B0 = *reinterpret_cast<const short8*>(Wb + c0 * 128 + kk * 32 + koff);
    short8 B1 = *reinterpret_cast<const short8*>(Wb + c1 * 128 + kk * 32 + koff);
#pragma unroll
    for (int mt = 0; mt < 6; ++mt) {
      short8 a = *reinterpret_cast<const short8*>(sagg + pl[mt] * HS + kk * 32 + koff);
      acc[mt][0] = __builtin_amdgcn_mfma_f32_16x16x32_f16(a, B0, acc[mt][0], 0, 0, 0);
      acc[mt][1] = __builtin_amdgcn_mfma_f32_16x16x32_f16(a, B1, acc[mt][1], 0, 0, 0);
    }
  }

  float bi0 = bias[c0], bi1 = bias[c1];
  float2* part = (float2*)smisc;            // [4][96]
  float2* mufin = (float2*)(smisc + 3072);  // [96]
#pragma unroll
  for (int mt = 0; mt < 6; ++mt) {
    float s[4], ss[4];
#pragma unroll
    for (int r = 0; r < 4; ++r) {
      float z0 = acc[mt][0][r] + bi0;
      float z1 = acc[mt][1][r] + bi1;
      acc[mt][0][r] = z0;
      acc[mt][1][r] = z1;
      s[r] = z0 + z1;
      ss[r] = fmaf(z0, z0, z1 * z1);
    }
#pragma unroll
    for (int m = 1; m <= 8; m <<= 1) {
#pragma unroll
      for (int r = 0; r < 4; ++r) {
        s[r] += __shfl_xor(s[r], m);
        ss[r] += __shfl_xor(ss[r], m);
      }
    }
    if (l15 == 0) {
#pragma unroll
      for (int r = 0; r < 4; ++r)
        part[w * CAPR + mt * 16 + l4 * 4 + r] = make_float2(s[r], ss[r]);
    }
  }
  __syncthreads();   // all MFMA reads of sh/sagg complete before this point
  if (threadIdx.x < CAPR) {
    int rr = threadIdx.x;
    float2 qa = part[0 * CAPR + rr], qb = part[1 * CAPR + rr];
    float2 qc = part[2 * CAPR + rr], qd = part[3 * CAPR + rr];
    float S = qa.x + qb.x + qc.x + qd.x;
    float SS = qa.y + qb.y + qc.y + qd.y;
    float mu = S * (1.f / 128.f);
    float rv = rsqrtf(SS * (1.f / 128.f) - mu * mu + EPSV);
    mufin[rr] = make_float2(mu, rv);
  }
  __syncthreads();
  float ga0 = gamma[c0], ga1 = gamma[c1], bt0 = beta[c0], bt1 = beta[c1];
#pragma unroll
  for (int mt = 0; mt < 6; ++mt) {
#pragma unroll
    for (int r = 0; r < 4; ++r) {
      int row = mt * 16 + l4 * 4 + r;
      float2 q = mufin[row];
      float v0 = fmaxf(fmaf((acc[mt][0][r] - q.x) * q.y, ga0, bt0), 0.f);
      float v1 = fmaxf(fmaf((acc[mt][1][r] - q.x) * q.y, ga1, bt1), 0.f);
      sh[row * HS + c0] = f2h(v0);
      sh[row * HS + c1] = f2h(v1);
    }
  }
  __syncthreads();
}

// ---- batched LDS segmax over one slot: 8 independent loads per wait, packed f16 max
// rows clamped to ls+min(k+j, n-1): always inside the same polyline -> idempotent for max
__device__ __forceinline__ unsigned int slot_max(
    const unsigned short* sh, int ls, int n, int lane)
{
  const unsigned short* base = sh + ls * HS + 2 * lane;
  unsigned int m = 0u;  // packed (+0.0, +0.0); values post-ReLU >= 0
  for (int k = 0; k < n; k += 8) {
    unsigned int v[8];
#pragma unroll
    for (int j = 0; j < 8; ++j) {
      int kk = k + j;
      kk = kk < n - 1 ? kk : n - 1;
      v[j] = *reinterpret_cast<const unsigned int*>(base + kk * HS);
    }
    unsigned int a = pkmax(v[0], v[1]);
    unsigned int b = pkmax(v[2], v[3]);
    unsigned int c = pkmax(v[4], v[5]);
    unsigned int d = pkmax(v[6], v[7]);
    m = pkmax(m, pkmax(pkmax(a, b), pkmax(c, d)));
  }
  return m;
}

// ---------------- fused kernel ----------------
__global__ __launch_bounds__(256, 3) void k_fused(
    const float* __restrict__ x, const int* __restrict__ perm,
    const unsigned int* __restrict__ cnt, const unsigned int* __restrict__ offsets,
    const int* __restrict__ gcount, const int* __restrict__ gplist,
    const float* __restrict__ W0, const float* __restrict__ b0,
    const float* __restrict__ g0, const float* __restrict__ be0,
    const unsigned short* __restrict__ Wt1, const unsigned short* __restrict__ Wb1,
    const float* __restrict__ b1, const float* __restrict__ g1, const float* __restrict__ be1,
    const unsigned short* __restrict__ Wt2, const unsigned short* __restrict__ Wb2,
    const float* __restrict__ b2, const float* __restrict__ g2, const float* __restrict__ be2,
    float* __restrict__ out)
{
  __shared__ unsigned short sh[CAPR * HS];    // 26112 B : h tile
  __shared__ unsigned short sagg[BCAP * HS];  // 17408 B : per-slot agg
  __shared__ char smisc[3840];                // xs (enc0) / part+mufin (layers)
  __shared__ short sl_off[BCAP], sl_n[BCAP];
  __shared__ int sl_p[BCAP];
  __shared__ int pid_loc[CAPR];
  __shared__ int s_rs, s_nrows;

  const int g = blockIdx.x;
  const int npoly0 = gcount[g];
  if (npoly0 <= 0) return;  // uniform exit before any barrier
  const int npoly = npoly0 > BCAP ? BCAP : npoly0;
  const int tid = threadIdx.x;
  const int lane = tid & 63;
  const int w = tid >> 6;
  const int l15 = lane & 15;
  const int l4 = lane >> 4;
  const int koff = l4 * 8;

  // ---- meta: row range + slot tables (wave 0) ----
  if (tid < 64) {
    int s = tid;
    int off = 0x7FFFFFFF, n = 0, end = 0, p = 0;
    if (s < npoly) {
      p = gplist[g * BCAP + s];
      off = (int)offsets[p];
      n = (int)cnt[p];
      if (n > BCAP) n = BCAP;
      end = off + n;
    }
    int rsv = off, rev = end;
#pragma unroll
    for (int m = 32; m >= 1; m >>= 1) {
      rsv = min(rsv, __shfl_xor(rsv, m));
      rev = max(rev, __shfl_xor(rev, m));
    }
    if (s == 0) { s_rs = rsv; s_nrows = min(rev - rsv, CAPR); }
    if (s < npoly) {
      int ls = off - rsv;
      sl_off[s] = (short)ls;
      sl_n[s] = (short)n;
      sl_p[s] = p;
      for (int k = 0; k < n; ++k)
        if (ls + k < CAPR) pid_loc[ls + k] = s;
    }
    int nr = min(rev - rsv, CAPR);
    for (int r = nr + s; r < CAPR; r += 64) pid_loc[r] = 0;
  }
  __syncthreads();
  const int rs = s_rs;
  const int nrows = s_nrows;

  // ---- gather x rows into LDS ----
  float* xs = (float*)smisc;  // [96][9]
  for (int e = tid; e < nrows * IN_DIM; e += 256) {
    int r = e / IN_DIM;
    int k = e - r * IN_DIM;
    unsigned o = (unsigned)perm[rs + r];
    if (o >= N_PTS) o = 0;  // safety clamp
    xs[e] = x[(size_t)o * IN_DIM + k];
  }
  __syncthreads();

  // ---- enc0: wave-per-row VALU matvec, 4 rows interleaved for ILP ----
  {
    float w0a[9], w0b[9];
#pragma unroll
    for (int k = 0; k < 9; ++k) {
      float2 t = *reinterpret_cast<const float2*>(W0 + k * 128 + 2 * lane);
      w0a[k] = t.x;
      w0b[k] = t.y;
    }
    float2 bb = *reinterpret_cast<const float2*>(b0 + 2 * lane);
    float2 gg = *reinterpret_cast<const float2*>(g0 + 2 * lane);
    float2 ee = *reinterpret_cast<const float2*>(be0 + 2 * lane);
#pragma unroll
    for (int it = 0; it < 6; ++it) {
      float z0[4], z1[4], s[4], ss[4];
      int rr[4];
#pragma unroll
      for (int u = 0; u < 4; ++u) {
        int r = w + 4 * (it * 4 + u);
        rr[u] = r;
        int rc = r < nrows ? r : 0;
        float a = bb.x, b = bb.y;
#pragma unroll
        for (int k = 0; k < 9; ++k) {
          float xv = xs[rc * 9 + k];
          a = fmaf(xv, w0a[k], a);
          b = fmaf(xv, w0b[k], b);
        }
        z0[u] = a;
        z1[u] = b;
        s[u] = a + b;
        ss[u] = fmaf(a, a, b * b);
      }
#pragma unroll
      for (int m = 1; m <= 32; m <<= 1) {
#pragma unroll
        for (int u = 0; u < 4; ++u) {
          s[u] += __shfl_xor(s[u], m);
          ss[u] += __shfl_xor(ss[u], m);
        }
      }
#pragma unroll
      for (int u = 0; u < 4; ++u) {
        if (rr[u] < nrows) {
          float mu = s[u] * (1.f / 128.f);
          float rv = rsqrtf(ss[u] * (1.f / 128.f) - mu * mu + EPSV);
          float v0 = fmaxf(fmaf((z0[u] - mu) * rv, gg.x, ee.x), 0.f);
          float v1 = fmaxf(fmaf((z1[u] - mu) * rv, gg.y, ee.y), 0.f);
          *reinterpret_cast<ushort2*>(sh + rr[u] * HS + 2 * lane) =
              make_ushort2(f2h(v0), f2h(v1));
        }
      }
    }
  }
  __syncthreads();  // h ready; xs dead

  // ---- segmax0 (LDS->LDS, batched) ----
  for (int s = w; s < npoly; s += 4) {
    unsigned int m = slot_max(sh, sl_off[s], sl_n[s], lane);
    *reinterpret_cast<unsigned int*>(sagg + s * HS + 2 * lane) = m;
  }
  __syncthreads();

  enc_layer(sh, sagg, pid_loc, smisc, Wt1, Wb1, b1, g1, be1, w, l15, l4, koff);

  // ---- segmax1 ----
  for (int s = w; s < npoly; s += 4) {
    unsigned int m = slot_max(sh, sl_off[s], sl_n[s], lane);
    *reinterpret_cast<unsigned int*>(sagg + s * HS + 2 * lane) = m;
  }
  __syncthreads();

  enc_layer(sh, sagg, pid_loc, smisc, Wt2, Wb2, b2, g2, be2, w, l15, l4, koff);

  // ---- segmax2: final -> global out (fp32) + arange tail ----
  for (int s = w; s < npoly; s += 4) {
    unsigned int m = slot_max(sh, sl_off[s], sl_n[s], lane);
    float2 f = make_float2(h2f((unsigned short)(m & 0xFFFFu)),
                           h2f((unsigned short)(m >> 16)));
    int p = sl_p[s];
    *reinterpret_cast<float2*>(out + (size_t)p * 128 + 2 * lane) = f;
    if (lane == 0) out[(size_t)P_POLY * 128 + p] = (float)p;
  }
}

// ws layout (bytes)
#define WS_CNT   0           // 204800
#define WS_OFF   204800      // 204800
#define WS_BTOT  409600      // 4096
#define WS_PERM  413696      // 2000000
#define WS_LIST  2413696     // 12800000
#define WS_GCNT  15213696    // 32768
#define WS_GPL   15246464    // 2000896
#define WS_W     17247360    // 131072
#define WS_NEED  17378432

__device__ __attribute__((aligned(256))) unsigned char g_fallback[WS_NEED];

extern "C" void kernel_launch(void* const* d_in, const int* in_sizes, int n_in,
                              void* d_out, int out_size, void* d_ws, size_t ws_size,
                              hipStream_t stream) {
  const float* x = (const float*)d_in[0];
  const int* ids = (const int*)d_in[1];
  const float* W0 = (const float*)d_in[2];
  const float* b0 = (const float*)d_in[3];
  const float* g0 = (const float*)d_in[4];
  const float* be0 = (const float*)d_in[5];
  const float* W1 = (const float*)d_in[6];
  const float* b1 = (const float*)d_in[7];
  const float* g1 = (const float*)d_in[8];
  const float* be1 = (const float*)d_in[9];
  const float* W2 = (const float*)d_in[10];
  const float* b2 = (const float*)d_in[11];
  const float* g2 = (const float*)d_in[12];
  const float* be2 = (const float*)d_in[13];

  char* ws = (char*)d_ws;
  if (ws_size < (size_t)WS_NEED) {
    void* p = nullptr;
    hipGetSymbolAddress(&p, HIP_SYMBOL(g_fallback));
    ws = (char*)p;
  }
  unsigned int* cnt = (unsigned int*)(ws + WS_CNT);
  unsigned int* offsets = (unsigned int*)(ws + WS_OFF);
  unsigned int* btot = (unsigned int*)(ws + WS_BTOT);
  int* perm = (int*)(ws + WS_PERM);
  int* list = (int*)(ws + WS_LIST);
  int* gcount = (int*)(ws + WS_GCNT);
  int* gplist = (int*)(ws + WS_GPL);
  unsigned short* Wt1 = (unsigned short*)(ws + WS_W);
  unsigned short* Wb1 = (unsigned short*)(ws + WS_W + 32768);
  unsigned short* Wt2 = (unsigned short*)(ws + WS_W + 65536);
  unsigned short* Wb2 = (unsigned short*)(ws + WS_W + 98304);
  float* out = (float*)d_out;

  hipMemsetAsync(cnt, 0, P_POLY * 4, stream);
  hipMemsetAsync(gcount, 0, 32768, stream);

  k_bucket<<<(N_PTS + 255) / 256, 256, 0, stream>>>(ids, cnt, list);
  k_scan1<<<196, 256, 0, stream>>>(cnt, btot);
  k_scan2<<<196, 256, 0, stream>>>(cnt, btot, list, offsets, perm, gcount, gplist);
  k_wprep<<<256, 256, 0, stream>>>(W1, W2, Wt1, Wb1, Wt2, Wb2);
  k_fused<<<NG, 256, 0, stream>>>(x, perm, cnt, offsets, gcount, gplist,
                                  W0, b0, g0, be0,
                                  Wt1, Wb1, b1, g1, be1,
                                  Wt2, Wb2, b2, g2, be2, out);
}

// Round 12
// 442.604 us; speedup vs baseline: 1.1574x; 1.1574x over previous
//
#include <hip/hip_runtime.h>
#include <hip/hip_bf16.h>
#include <hip/hip_fp16.h>

#define N_PTS 500000
#define P_POLY 50000
#define IN_DIM 9
#define HDIM 128
#define EPSV 1e-5f
#define NG 7813            // ceil(N_PTS / 64) row windows
#define CAPR 96            // row capacity per group (64 + max polyline len margin)
#define SLOTS 32           // max polylines per group (avg ~6.4)
#define HS 136             // LDS row stride in elems (272 B)

typedef __attribute__((ext_vector_type(8))) short short8;
typedef __attribute__((ext_vector_type(4))) float floatx4;

__device__ __forceinline__ unsigned short f2h(float f) {
  return __half_as_ushort(__float2half(f));
}
__device__ __forceinline__ float h2f(unsigned short u) {
  return __half2float(__ushort_as_half(u));
}
// packed f16 max on raw bits
__device__ __forceinline__ unsigned int pkmax(unsigned int a, unsigned int b) {
  unsigned int r;
  asm("v_pk_max_f16 %0, %1, %2" : "=v"(r) : "v"(a), "v"(b));
  return r;
}

// ---------------- count: per-polyline sizes ----------------
__global__ __launch_bounds__(256) void k_count(
    const int* __restrict__ ids, unsigned int* __restrict__ cnt)
{
  int i = blockIdx.x * blockDim.x + threadIdx.x;
  if (i < N_PTS) atomicAdd(&cnt[ids[i]], 1u);
}

// ---------------- scan stage 1 (blocks 0..195) + W prep (blocks 196..323) ----------------
__global__ __launch_bounds__(256) void k_scanwp(
    const unsigned int* __restrict__ cnt, unsigned int* __restrict__ btot,
    const float* __restrict__ W1, const float* __restrict__ W2,
    unsigned short* __restrict__ Wt1, unsigned short* __restrict__ Wb1,
    unsigned short* __restrict__ Wt2, unsigned short* __restrict__ Wb2)
{
  if (blockIdx.x < 196) {
    __shared__ unsigned int s[256];
    int t = threadIdx.x;
    int i = blockIdx.x * 256 + t;
    s[t] = (i < P_POLY) ? cnt[i] : 0u;
    __syncthreads();
    for (int d = 128; d > 0; d >>= 1) {
      if (t < d) s[t] += s[t + d];
      __syncthreads();
    }
    if (t == 0) btot[blockIdx.x] = s[0];
  } else {
    int bw = blockIdx.x - 196;  // 0..127
#pragma unroll
    for (int t = 0; t < 2; ++t) {
      int idx = (bw * 2 + t) * 256 + threadIdx.x;  // 0..65535
      int sel = idx >> 14;
      int e = idx & 16383;
      int c = e & 127;
      int k = e >> 7;
      const float* W = (sel < 2) ? W1 : W2;
      unsigned short* O = sel == 0 ? Wt1 : sel == 1 ? Wb1 : sel == 2 ? Wt2 : Wb2;
      int kg = k + ((sel & 1) ? 128 : 0);
      O[c * 128 + k] = f2h(W[kg * 128 + c]);
    }
  }
}

// ---------------- scan stage 2: exclusive offsets + working copy ----------------
__global__ __launch_bounds__(256) void k_scan2(
    const unsigned int* __restrict__ cnt, const unsigned int* __restrict__ btot,
    unsigned int* __restrict__ offsets, unsigned int* __restrict__ woff)
{
  __shared__ unsigned int s[256];
  __shared__ unsigned int sbase;
  int b = blockIdx.x, t = threadIdx.x;
  int i = b * 256 + t;
  unsigned int v = (i < P_POLY) ? cnt[i] : 0u;
  s[t] = v;
  __syncthreads();
  for (int d = 1; d < 256; d <<= 1) {
    unsigned int tmp = (t >= d) ? s[t - d] : 0u;
    __syncthreads();
    s[t] += tmp;
    __syncthreads();
  }
  unsigned int incl = s[t];
  if (t == 0) {
    unsigned int base = 0;
    for (int j = 0; j < b; ++j) base += btot[j];
    sbase = base;
  }
  __syncthreads();
  unsigned int off = sbase + incl - v;
  if (i < P_POLY) {
    offsets[i] = off;
    woff[i] = off;
  }
}

// ---------------- place: perm (sorted->orig) + pid_perm (sorted->id) ----------------
__global__ __launch_bounds__(256) void k_place(
    const int* __restrict__ ids, unsigned int* __restrict__ woff,
    int* __restrict__ perm, int* __restrict__ pid_perm)
{
  int i = blockIdx.x * blockDim.x + threadIdx.x;
  if (i < N_PTS) {
    int id = ids[i];
    unsigned pos = atomicAdd(&woff[id], 1u);
    perm[pos] = i;
    pid_perm[pos] = id;
  }
}

// ---------------- fused per-group network: MFMA layer helper ----------------
__device__ __forceinline__ void enc_layer(
    unsigned short* sh, const unsigned short* sagg, const int* pid_loc, char* smisc,
    const unsigned short* __restrict__ Wt, const unsigned short* __restrict__ Wb,
    const float* __restrict__ bias, const float* __restrict__ gamma,
    const float* __restrict__ beta, int w, int l15, int l4, int koff, int nrows)
{
  const int c0 = w * 32 + l15;
  const int c1 = c0 + 16;
  const int mtmax = (nrows + 15) >> 4;  // uniform 1..6
  floatx4 acc[6][2];
#pragma unroll
  for (int mt = 0; mt < 6; ++mt) {
    acc[mt][0] = (floatx4){0.f, 0.f, 0.f, 0.f};
    acc[mt][1] = (floatx4){0.f, 0.f, 0.f, 0.f};
  }
  int pl[6];
#pragma unroll
  for (int mt = 0; mt < 6; ++mt) pl[mt] = pid_loc[mt * 16 + l15];

#pragma unroll
  for (int kk = 0; kk < 4; ++kk) {
    short8 B0 = *reinterpret_cast<const short8*>(Wt + c0 * 128 + kk * 32 + koff);
    short8 B1 = *reinterpret_cast<const short8*>(Wt + c1 * 128 + kk * 32 + koff);
#pragma unroll
    for (int mt = 0; mt < 6; ++mt) {
      if (mt < mtmax) {
        short8 a = *reinterpret_cast<const short8*>(sh + (mt * 16 + l15) * HS + kk * 32 + koff);
        acc[mt][0] = __builtin_amdgcn_mfma_f32_16x16x32_f16(a, B0, acc[mt][0], 0, 0, 0);
        acc[mt][1] = __builtin_amdgcn_mfma_f32_16x16x32_f16(a, B1, acc[mt][1], 0, 0, 0);
      }
    }
  }
#pragma unroll
  for (int kk = 0; kk < 4; ++kk) {
    short8 B0 = *reinterpret_cast<const short8*>(Wb + c0 * 128 + kk * 32 + koff);
    short8 B1 = *reinterpret_cast<const short8*>(Wb + c1 * 128 + kk * 32 + koff);
#pragma unroll
    for (int mt = 0; mt < 6; ++mt) {
      if (mt < mtmax) {
        short8 a = *reinterpret_cast<const short8*>(sagg + pl[mt] * HS + kk * 32 + koff);
        acc[mt][0] = __builtin_amdgcn_mfma_f32_16x16x32_f16(a, B0, acc[mt][0], 0, 0, 0);
        acc[mt][1] = __builtin_amdgcn_mfma_f32_16x16x32_f16(a, B1, acc[mt][1], 0, 0, 0);
      }
    }
  }

  float bi0 = bias[c0], bi1 = bias[c1];
  float2* part = (float2*)smisc;            // [4][96]
  float2* mufin = (float2*)(smisc + 3072);  // [96]
#pragma unroll
  for (int mt = 0; mt < 6; ++mt) {
    if (mt < mtmax) {
      float s[4], ss[4];
#pragma unroll
      for (int r = 0; r < 4; ++r) {
        float z0 = acc[mt][0][r] + bi0;
        float z1 = acc[mt][1][r] + bi1;
        acc[mt][0][r] = z0;
        acc[mt][1][r] = z1;
        s[r] = z0 + z1;
        ss[r] = fmaf(z0, z0, z1 * z1);
      }
#pragma unroll
      for (int m = 1; m <= 8; m <<= 1) {
#pragma unroll
        for (int r = 0; r < 4; ++r) {
          s[r] += __shfl_xor(s[r], m);
          ss[r] += __shfl_xor(ss[r], m);
        }
      }
      if (l15 == 0) {
#pragma unroll
        for (int r = 0; r < 4; ++r)
          part[w * CAPR + mt * 16 + l4 * 4 + r] = make_float2(s[r], ss[r]);
      }
    }
  }
  __syncthreads();
  if (threadIdx.x < CAPR) {
    int rr = threadIdx.x;
    float2 qa = part[0 * CAPR + rr], qb = part[1 * CAPR + rr];
    float2 qc = part[2 * CAPR + rr], qd = part[3 * CAPR + rr];
    float S = qa.x + qb.x + qc.x + qd.x;
    float SS = qa.y + qb.y + qc.y + qd.y;
    float mu = S * (1.f / 128.f);
    float rv = rsqrtf(SS * (1.f / 128.f) - mu * mu + EPSV);
    mufin[rr] = make_float2(mu, rv);
  }
  __syncthreads();
  float ga0 = gamma[c0], ga1 = gamma[c1], bt0 = beta[c0], bt1 = beta[c1];
#pragma unroll
  for (int mt = 0; mt < 6; ++mt) {
    if (mt < mtmax) {
#pragma unroll
      for (int r = 0; r < 4; ++r) {
        int row = mt * 16 + l4 * 4 + r;
        float2 q = mufin[row];
        float v0 = fmaxf(fmaf((acc[mt][0][r] - q.x) * q.y, ga0, bt0), 0.f);
        float v1 = fmaxf(fmaf((acc[mt][1][r] - q.x) * q.y, ga1, bt1), 0.f);
        sh[row * HS + c0] = f2h(v0);
        sh[row * HS + c1] = f2h(v1);
      }
    }
  }
  __syncthreads();
}

// ---- batched LDS segmax over one slot; clamp-idempotent, packed f16 max ----
__device__ __forceinline__ unsigned int slot_max(
    const unsigned short* sh, int ls, int n, int lane)
{
  const unsigned short* base = sh + ls * HS + 2 * lane;
  unsigned int m = 0u;  // values post-ReLU >= 0
  for (int k = 0; k < n; k += 8) {
    unsigned int v[8];
#pragma unroll
    for (int j = 0; j < 8; ++j) {
      int kk = k + j;
      kk = kk < n - 1 ? kk : n - 1;
      v[j] = *reinterpret_cast<const unsigned int*>(base + kk * HS);
    }
    unsigned int a = pkmax(v[0], v[1]);
    unsigned int b = pkmax(v[2], v[3]);
    unsigned int c = pkmax(v[4], v[5]);
    unsigned int d = pkmax(v[6], v[7]);
    m = pkmax(m, pkmax(pkmax(a, b), pkmax(c, d)));
  }
  return m;
}

// ---------------- fused kernel ----------------
__global__ __launch_bounds__(256, 4) void k_fused(
    const float* __restrict__ x, const int* __restrict__ perm,
    const int* __restrict__ pid_perm, const unsigned int* __restrict__ offsets,
    const float* __restrict__ W0, const float* __restrict__ b0,
    const float* __restrict__ g0, const float* __restrict__ be0,
    const unsigned short* __restrict__ Wt1, const unsigned short* __restrict__ Wb1,
    const float* __restrict__ b1, const float* __restrict__ g1, const float* __restrict__ be1,
    const unsigned short* __restrict__ Wt2, const unsigned short* __restrict__ Wb2,
    const float* __restrict__ b2, const float* __restrict__ g2, const float* __restrict__ be2,
    float* __restrict__ out)
{
  __shared__ unsigned short sh[CAPR * HS];     // 26112 B
  __shared__ unsigned short sagg[SLOTS * HS];  // 8704 B
  __shared__ char smisc[3840];                 // xs / part+mufin
  __shared__ short sl_off[SLOTS], sl_n[SLOTS];
  __shared__ int pid_loc[CAPR];

  const int g = blockIdx.x;
  const int j1 = g * 64;
  const int j2 = j1 + 64;

  // ---- meta: contiguous polyline-ID range of this window (uniform, ~6 scalar loads) ----
  int q = pid_perm[j1];
  int p_lo = q + ((int)offsets[q] < j1 ? 1 : 0);
  int p_hi, endrow;
  if (j2 >= N_PTS) {
    p_hi = P_POLY - 1;
    endrow = N_PTS;
  } else {
    int q2 = pid_perm[j2];
    p_hi = ((int)offsets[q2] < j2) ? q2 : q2 - 1;
    endrow = (p_hi + 1 < P_POLY) ? (int)offsets[p_hi + 1] : N_PTS;
  }
  int npoly = p_hi - p_lo + 1;
  if (npoly <= 0) return;  // uniform, before any barrier
  if (npoly > SLOTS) npoly = SLOTS;
  const int rs = (int)offsets[p_lo];
  int nrows = endrow - rs;
  if (nrows > CAPR) nrows = CAPR;

  const int tid = threadIdx.x;
  const int lane = tid & 63;
  const int w = tid >> 6;
  const int l15 = lane & 15;
  const int l4 = lane >> 4;
  const int koff = l4 * 8;

  // ---- x gather (issued first; all threads) ----
  float* xs = (float*)smisc;  // [96][9]
  for (int e = tid; e < nrows * IN_DIM; e += 256) {
    int r = e / IN_DIM;
    int k = e - r * IN_DIM;
    xs[e] = x[(size_t)perm[rs + r] * IN_DIM + k];
  }
  // ---- slot tables + pid_loc (parallel, coalesced) ----
  for (int s = tid; s < npoly; s += 256) {
    int o = (int)offsets[p_lo + s];
    int e2 = (p_lo + s + 1 < P_POLY) ? (int)offsets[p_lo + s + 1] : N_PTS;
    int ls = o - rs;
    int n = e2 - o;
    if (n > CAPR - ls) n = CAPR - ls;  // safety
    sl_off[s] = (short)ls;
    sl_n[s] = (short)n;
  }
  for (int r = tid; r < CAPR; r += 256) {
    int v = 0;
    if (r < nrows) {
      v = pid_perm[rs + r] - p_lo;
      if (v >= SLOTS) v = SLOTS - 1;
      if (v < 0) v = 0;
    }
    pid_loc[r] = v;
  }
  __syncthreads();

  // ---- enc0: wave-per-row VALU matvec, 4 rows interleaved, padded its skipped ----
  {
    float w0a[9], w0b[9];
#pragma unroll
    for (int k = 0; k < 9; ++k) {
      float2 t = *reinterpret_cast<const float2*>(W0 + k * 128 + 2 * lane);
      w0a[k] = t.x;
      w0b[k] = t.y;
    }
    float2 bb = *reinterpret_cast<const float2*>(b0 + 2 * lane);
    float2 gg = *reinterpret_cast<const float2*>(g0 + 2 * lane);
    float2 ee = *reinterpret_cast<const float2*>(be0 + 2 * lane);
#pragma unroll
    for (int it = 0; it < 6; ++it) {
      if (it * 16 < nrows) {
        float z0[4], z1[4], s[4], ss[4];
        int rr[4];
#pragma unroll
        for (int u = 0; u < 4; ++u) {
          int r = w + 4 * (it * 4 + u);
          rr[u] = r;
          int rc = r < nrows ? r : 0;
          float a = bb.x, b = bb.y;
#pragma unroll
          for (int k = 0; k < 9; ++k) {
            float xv = xs[rc * 9 + k];
            a = fmaf(xv, w0a[k], a);
            b = fmaf(xv, w0b[k], b);
          }
          z0[u] = a;
          z1[u] = b;
          s[u] = a + b;
          ss[u] = fmaf(a, a, b * b);
        }
#pragma unroll
        for (int m = 1; m <= 32; m <<= 1) {
#pragma unroll
          for (int u = 0; u < 4; ++u) {
            s[u] += __shfl_xor(s[u], m);
            ss[u] += __shfl_xor(ss[u], m);
          }
        }
#pragma unroll
        for (int u = 0; u < 4; ++u) {
          if (rr[u] < nrows) {
            float mu = s[u] * (1.f / 128.f);
            float rv = rsqrtf(ss[u] * (1.f / 128.f) - mu * mu + EPSV);
            float v0 = fmaxf(fmaf((z0[u] - mu) * rv, gg.x, ee.x), 0.f);
            float v1 = fmaxf(fmaf((z1[u] - mu) * rv, gg.y, ee.y), 0.f);
            *reinterpret_cast<ushort2*>(sh + rr[u] * HS + 2 * lane) =
                make_ushort2(f2h(v0), f2h(v1));
          }
        }
      }
    }
  }
  __syncthreads();

  // ---- segmax0 ----
  for (int s = w; s < npoly; s += 4) {
    unsigned int m = slot_max(sh, sl_off[s], sl_n[s], lane);
    *reinterpret_cast<unsigned int*>(sagg + s * HS + 2 * lane) = m;
  }
  __syncthreads();

  enc_layer(sh, sagg, pid_loc, smisc, Wt1, Wb1, b1, g1, be1, w, l15, l4, koff, nrows);

  // ---- segmax1 ----
  for (int s = w; s < npoly; s += 4) {
    unsigned int m = slot_max(sh, sl_off[s], sl_n[s], lane);
    *reinterpret_cast<unsigned int*>(sagg + s * HS + 2 * lane) = m;
  }
  __syncthreads();

  enc_layer(sh, sagg, pid_loc, smisc, Wt2, Wb2, b2, g2, be2, w, l15, l4, koff, nrows);

  // ---- segmax2: final -> global out (fp32) + arange tail ----
  for (int s = w; s < npoly; s += 4) {
    unsigned int m = slot_max(sh, sl_off[s], sl_n[s], lane);
    float2 f = make_float2(h2f((unsigned short)(m & 0xFFFFu)),
                           h2f((unsigned short)(m >> 16)));
    int p = p_lo + s;
    *reinterpret_cast<float2*>(out + (size_t)p * 128 + 2 * lane) = f;
    if (lane == 0) out[(size_t)P_POLY * 128 + p] = (float)p;
  }
}

// ws layout (bytes)
#define WS_CNT   0           // 200000 -> pad 204800
#define WS_OFF   204800      // 200000 -> pad 204800
#define WS_WOFF  409600      // 200000 -> pad 204800
#define WS_BTOT  614400      // 4096
#define WS_PERM  618496      // 2000000
#define WS_PID   2618496     // 2000000
#define WS_W     4618496     // 131072
#define WS_NEED  4749568

__device__ __attribute__((aligned(256))) unsigned char g_fallback[WS_NEED];

extern "C" void kernel_launch(void* const* d_in, const int* in_sizes, int n_in,
                              void* d_out, int out_size, void* d_ws, size_t ws_size,
                              hipStream_t stream) {
  const float* x = (const float*)d_in[0];
  const int* ids = (const int*)d_in[1];
  const float* W0 = (const float*)d_in[2];
  const float* b0 = (const float*)d_in[3];
  const float* g0 = (const float*)d_in[4];
  const float* be0 = (const float*)d_in[5];
  const float* W1 = (const float*)d_in[6];
  const float* b1 = (const float*)d_in[7];
  const float* g1 = (const float*)d_in[8];
  const float* be1 = (const float*)d_in[9];
  const float* W2 = (const float*)d_in[10];
  const float* b2 = (const float*)d_in[11];
  const float* g2 = (const float*)d_in[12];
  const float* be2 = (const float*)d_in[13];

  char* ws = (char*)d_ws;
  if (ws_size < (size_t)WS_NEED) {
    void* p = nullptr;
    hipGetSymbolAddress(&p, HIP_SYMBOL(g_fallback));
    ws = (char*)p;
  }
  unsigned int* cnt = (unsigned int*)(ws + WS_CNT);
  unsigned int* offsets = (unsigned int*)(ws + WS_OFF);
  unsigned int* woff = (unsigned int*)(ws + WS_WOFF);
  unsigned int* btot = (unsigned int*)(ws + WS_BTOT);
  int* perm = (int*)(ws + WS_PERM);
  int* pid_perm = (int*)(ws + WS_PID);
  unsigned short* Wt1 = (unsigned short*)(ws + WS_W);
  unsigned short* Wb1 = (unsigned short*)(ws + WS_W + 32768);
  unsigned short* Wt2 = (unsigned short*)(ws + WS_W + 65536);
  unsigned short* Wb2 = (unsigned short*)(ws + WS_W + 98304);
  float* out = (float*)d_out;

  hipMemsetAsync(cnt, 0, P_POLY * 4, stream);
  k_count<<<(N_PTS + 255) / 256, 256, 0, stream>>>(ids, cnt);
  k_scanwp<<<324, 256, 0, stream>>>(cnt, btot, W1, W2, Wt1, Wb1, Wt2, Wb2);
  k_scan2<<<196, 256, 0, stream>>>(cnt, btot, offsets, woff);
  k_place<<<(N_PTS + 255) / 256, 256, 0, stream>>>(ids, woff, perm, pid_perm);
  k_fused<<<NG, 256, 0, stream>>>(x, perm, pid_perm, offsets,
                                  W0, b0, g0, be0,
                                  Wt1, Wb1, b1, g1, be1,
                                  Wt2, Wb2, b2, g2, be2, out);
}